// Round 5
// baseline (227.167 us; speedup 1.0000x reference)
//
#include <hip/hip_runtime.h>
#include <hip/hip_bf16.h>
#include <cstddef>

#define NB  4
#define NC  256
#define NN  4096
#define DQK 32
#define MT  64      // query rows per flash block (16 per wave)
#define JT  64      // key tile per iteration
#define PSTR 72     // P row stride in bf16
#define XSTR 40     // proj LDS row stride in bf16 (80 B rows, 16B-aligned b128)

typedef __attribute__((ext_vector_type(8))) short short8;
typedef __attribute__((ext_vector_type(4))) float f32x4;

#define MFMA16(a, b, c) __builtin_amdgcn_mfma_f32_16x16x32_bf16((a), (b), (c), 0, 0, 0)

__device__ inline unsigned pk2bf(float a, float b) {
  __hip_bfloat162 h = __float22bfloat162_rn(make_float2(a, b));
  unsigned u;
  __builtin_memcpy(&u, &h, 4);
  return u;
}

// ---- W convert: [Wq(32);Wk(32);Wv(256)] f32 -> W16[320][256] bf16 ----
__global__ __launch_bounds__(256) void wcvt_kernel(
    const float* __restrict__ Wq, const float* __restrict__ Wk,
    const float* __restrict__ Wv, __hip_bfloat16* __restrict__ W16) {
  const int id4 = (blockIdx.x * 256 + threadIdx.x) * 4;   // 80 blocks -> 81920
  const int row = id4 >> 8, col = id4 & 255;
  const float* src = (row < 32) ? Wq + row * 256
                   : (row < 64) ? Wk + (row - 32) * 256
                                : Wv + (row - 64) * 256;
  float4 vv = *(const float4*)(src + col);
  *(uint2*)(W16 + id4) = make_uint2(pk2bf(vv.x, vv.y), pk2bf(vv.z, vv.w));
}

// ---- fused proj: D[320 o][64 n] per block, x read directly (no transpose) ----
// Wave w owns o rows [w*80, w*80+80). B-frags (x) from LDS, A-frags (W16) from L2.
__global__ __launch_bounds__(256, 1) void proj_kernel(
    const float* __restrict__ x, const __hip_bfloat16* __restrict__ W16,
    const float* __restrict__ bq, const float* __restrict__ bk,
    const float* __restrict__ bv, __hip_bfloat16* __restrict__ q,
    __hip_bfloat16* __restrict__ kT, __hip_bfloat16* __restrict__ v) {
  __shared__ __hip_bfloat16 Xs[64 * XSTR];   // 5120 B
  const int t = threadIdx.x;
  const int b = blockIdx.y, n0 = blockIdx.x * 64;
  const int w = __builtin_amdgcn_readfirstlane(t >> 6);
  const int ln = t & 15, quad = (t & 63) >> 4;
  const int sn = t & 63, scg = t >> 6;   // staging: n lane, c-group

  f32x4 zero4 = {0.f, 0.f, 0.f, 0.f};
  f32x4 acc[5][4];
#pragma unroll
  for (int i = 0; i < 5; ++i)
#pragma unroll
    for (int j = 0; j < 4; ++j) acc[i][j] = zero4;

  const float* xsrc = x + (size_t)b * NC * NN + n0 + sn;
  float xr[8];
#pragma unroll
  for (int i = 0; i < 8; ++i) xr[i] = xsrc[(size_t)(scg * 8 + i) * NN];

  for (int k0 = 0; k0 < NC; k0 += 32) {
    unsigned px[4];
#pragma unroll
    for (int i = 0; i < 4; ++i) px[i] = pk2bf(xr[2 * i], xr[2 * i + 1]);
    __syncthreads();                       // prior step's LDS reads done
    *(uint4*)&Xs[sn * XSTR + scg * 8] = make_uint4(px[0], px[1], px[2], px[3]);
    __syncthreads();                       // writes visible
    const int kn = k0 + 32;
    if (kn < NC) {
#pragma unroll
      for (int i = 0; i < 8; ++i) xr[i] = xsrc[(size_t)(kn + scg * 8 + i) * NN];
    }
    short8 af[5], bfr[4];
#pragma unroll
    for (int ot = 0; ot < 5; ++ot)
      af[ot] = *(const short8*)(W16 + (size_t)(w * 80 + ot * 16 + ln) * NC + k0 + quad * 8);
#pragma unroll
    for (int nt = 0; nt < 4; ++nt)
      bfr[nt] = *(const short8*)&Xs[(nt * 16 + ln) * XSTR + quad * 8];
#pragma unroll
    for (int ot = 0; ot < 5; ++ot)
#pragma unroll
      for (int nt = 0; nt < 4; ++nt)
        acc[ot][nt] = MFMA16(af[ot], bfr[nt], acc[ot][nt]);
  }

  // epilogue: rows [0,32)->q[b][n][o], [32,64)->kT[b][n][o], [64,320)->v[b][c][n]
#pragma unroll
  for (int ot = 0; ot < 5; ++ot) {
    const int gbase = w * 80 + ot * 16;    // wave-uniform
    if (gbase < 32) {
#pragma unroll
      for (int nt = 0; nt < 4; ++nt)
#pragma unroll
        for (int r = 0; r < 4; ++r) {
          const int row = gbase + quad * 4 + r;
          q[((size_t)b * NN + n0 + nt * 16 + ln) * DQK + row] =
              __hip_bfloat16(acc[ot][nt][r] + bq[row]);
        }
    } else if (gbase < 64) {
#pragma unroll
      for (int nt = 0; nt < 4; ++nt)
#pragma unroll
        for (int r = 0; r < 4; ++r) {
          const int row = gbase - 32 + quad * 4 + r;
          kT[((size_t)b * NN + n0 + nt * 16 + ln) * DQK + row] =
              __hip_bfloat16(acc[ot][nt][r] + bk[row]);
        }
    } else {
#pragma unroll
      for (int nt = 0; nt < 4; ++nt)
#pragma unroll
        for (int r = 0; r < 4; ++r) {
          const int c = gbase - 64 + quad * 4 + r;
          v[((size_t)b * NC + c) * NN + n0 + nt * 16 + ln] =
              __hip_bfloat16(acc[ot][nt][r] + bv[c]);
        }
    }
  }
}

// ---- wave-local flash. SPLIT=1: half j-range, partial (O,m,l) out. ----
template <int SPLIT>
__global__ __launch_bounds__(256, 1) void flash_kernel(
    const __hip_bfloat16* __restrict__ q, const __hip_bfloat16* __restrict__ kt,
    const __hip_bfloat16* __restrict__ v, const float* __restrict__ x,
    const float* __restrict__ gamma, float* __restrict__ out,
    float* __restrict__ pO, float* __restrict__ pM, float* __restrict__ pL) {
  __shared__ __hip_bfloat16 Ps[2][MT * PSTR];
  __shared__ float arow[2][MT];
  __shared__ float lrow[MT];

  const int t  = threadIdx.x;
  const int bi = blockIdx.x;
  const int b     = (bi & 7) >> 1;
  const int jh    = SPLIT ? (bi & 1) : 0;
  const int mtile = SPLIT ? (bi >> 3) : (((bi & 1) * 32) + (bi >> 3));
  const int m0    = mtile * MT;
  const int jbeg  = jh * (SPLIT ? NN / 2 : 0);
  const int jend  = SPLIT ? jbeg + NN / 2 : NN;

  const int w    = __builtin_amdgcn_readfirstlane(t >> 6);
  const int ln   = t & 15;
  const int quad = (t & 63) >> 4;

  const __hip_bfloat16* kb_base = kt + (size_t)b * NN * DQK;
  const __hip_bfloat16* v_base  = v + (size_t)b * NC * NN;

  const short8 qa =
      *(const short8*)(q + ((size_t)b * NN + m0 + w * 16 + ln) * DQK + quad * 8);

  float mreg[4], lreg[4];
#pragma unroll
  for (int r = 0; r < 4; ++r) { mreg[r] = -3.0e38f; lreg[r] = 0.f; }

  f32x4 zero4 = {0.f, 0.f, 0.f, 0.f};
  f32x4 acc[4][4];   // [ct][mt]: rows c = w*64+ct*16+quad*4+r, cols m = mt*16+ln
#pragma unroll
  for (int ct = 0; ct < 4; ++ct)
#pragma unroll
    for (int mt = 0; mt < 4; ++mt) acc[ct][mt] = zero4;

  short8 kb[4];
#pragma unroll
  for (int jt = 0; jt < 4; ++jt)
    kb[jt] = *(const short8*)(kb_base + (size_t)(jbeg + jt * 16 + ln) * DQK + quad * 8);

  int buf = 0;
  for (int j0 = jbeg; j0 < jend; j0 += JT, buf ^= 1) {
    // S = Q.K^T (registers)
    f32x4 sf[4];
#pragma unroll
    for (int jt = 0; jt < 4; ++jt) sf[jt] = MFMA16(qa, kb[jt], zero4);

    // prefetch next K + this iter's V
    const int jn = j0 + JT;
    short8 kbn[4];
    if (jn < jend) {
#pragma unroll
      for (int jt = 0; jt < 4; ++jt)
        kbn[jt] = *(const short8*)(kb_base + (size_t)(jn + jt * 16 + ln) * DQK + quad * 8);
    }
    short8 va[4][2];
#pragma unroll
    for (int ct = 0; ct < 4; ++ct)
#pragma unroll
      for (int ks = 0; ks < 2; ++ks)
        va[ct][ks] = *(const short8*)(v_base +
            (size_t)(w * 64 + ct * 16 + ln) * NN + j0 + ks * 32 + quad * 8);

    // wave-local online softmax
    float rmax[4];
#pragma unroll
    for (int r = 0; r < 4; ++r)
      rmax[r] = fmaxf(fmaxf(sf[0][r], sf[1][r]), fmaxf(sf[2][r], sf[3][r]));
#pragma unroll
    for (int off = 1; off < 16; off <<= 1)
#pragma unroll
      for (int r = 0; r < 4; ++r)
        rmax[r] = fmaxf(rmax[r], __shfl_xor(rmax[r], off));
    float alpha[4];
#pragma unroll
    for (int r = 0; r < 4; ++r) {
      const float mn = fmaxf(mreg[r], rmax[r]);
      alpha[r] = __expf(mreg[r] - mn);
      mreg[r] = mn;
    }
    float e[4][4], rsum[4];
#pragma unroll
    for (int r = 0; r < 4; ++r) rsum[r] = 0.f;
#pragma unroll
    for (int jt = 0; jt < 4; ++jt)
#pragma unroll
      for (int r = 0; r < 4; ++r) {
        e[jt][r] = __expf(sf[jt][r] - mreg[r]);
        rsum[r] += e[jt][r];
      }
#pragma unroll
    for (int off = 1; off < 16; off <<= 1)
#pragma unroll
      for (int r = 0; r < 4; ++r) rsum[r] += __shfl_xor(rsum[r], off);
#pragma unroll
    for (int r = 0; r < 4; ++r) lreg[r] = lreg[r] * alpha[r] + rsum[r];

    // write P tile + alpha
#pragma unroll
    for (int jt = 0; jt < 4; ++jt)
#pragma unroll
      for (int r = 0; r < 4; ++r)
        Ps[buf][(w * 16 + quad * 4 + r) * PSTR + jt * 16 + ln] = __hip_bfloat16(e[jt][r]);
    if (ln == 0) {
#pragma unroll
      for (int r = 0; r < 4; ++r) arow[buf][w * 16 + quad * 4 + r] = alpha[r];
    }
    __syncthreads();

    // PV
    float av[4];
#pragma unroll
    for (int mt = 0; mt < 4; ++mt) av[mt] = arow[buf][mt * 16 + ln];
#pragma unroll
    for (int ct = 0; ct < 4; ++ct)
#pragma unroll
      for (int mt = 0; mt < 4; ++mt) acc[ct][mt] *= av[mt];

#pragma unroll
    for (int ks = 0; ks < 2; ++ks) {
      short8 pb[4];
#pragma unroll
      for (int mt = 0; mt < 4; ++mt)
        pb[mt] = *(const short8*)&Ps[buf][(mt * 16 + ln) * PSTR + ks * 32 + quad * 8];
#pragma unroll
      for (int ct = 0; ct < 4; ++ct)
#pragma unroll
        for (int mt = 0; mt < 4; ++mt)
          acc[ct][mt] = MFMA16(va[ct][ks], pb[mt], acc[ct][mt]);
    }

#pragma unroll
    for (int jt = 0; jt < 4; ++jt) kb[jt] = kbn[jt];
  }

  if (SPLIT) {
    // partial stores: unnormalized O + per-row m,l
    const size_t blk = (size_t)(b * 2 + jh) * 64 + mtile;
    if (ln == 0) {
#pragma unroll
      for (int r = 0; r < 4; ++r) {
        pM[blk * 64 + w * 16 + quad * 4 + r] = mreg[r];
        pL[blk * 64 + w * 16 + quad * 4 + r] = lreg[r];
      }
    }
#pragma unroll
    for (int ct = 0; ct < 4; ++ct)
#pragma unroll
      for (int r = 0; r < 4; ++r) {
        const int c = w * 64 + ct * 16 + quad * 4 + r;
        float* prow = pO + (blk * NC + c) * 64;
#pragma unroll
        for (int mt = 0; mt < 4; ++mt)
          prow[mt * 16 + ln] = acc[ct][mt][r];
      }
  } else {
    if (ln == 0) {
#pragma unroll
      for (int r = 0; r < 4; ++r) lrow[w * 16 + quad * 4 + r] = lreg[r];
    }
    __syncthreads();
    const float g0 = gamma[0];
    float li[4];
#pragma unroll
    for (int mt = 0; mt < 4; ++mt) li[mt] = 1.f / lrow[mt * 16 + ln];
#pragma unroll
    for (int ct = 0; ct < 4; ++ct)
#pragma unroll
      for (int r = 0; r < 4; ++r) {
        const int c = w * 64 + ct * 16 + quad * 4 + r;
        const float* xr = x + ((size_t)b * NC + c) * NN + m0;
        float* orow = out + ((size_t)b * NC + c) * NN + m0;
#pragma unroll
        for (int mt = 0; mt < 4; ++mt) {
          const int m = mt * 16 + ln;
          orow[m] = g0 * (acc[ct][mt][r] * li[mt]) + xr[m];
        }
      }
  }
}

// ---- combine: merge 2 j-halves, normalize, gamma*()+x ----
__global__ __launch_bounds__(256) void combine_kernel(
    const float* __restrict__ pO, const float* __restrict__ pM,
    const float* __restrict__ pL, const float* __restrict__ x,
    const float* __restrict__ gamma, float* __restrict__ out) {
  __shared__ float s0[64], s1[64];
  const int t = threadIdx.x;
  const int mtile = blockIdx.x, ch = blockIdx.y, b = blockIdx.z;

  if (t < 64) {
    const size_t b0 = ((size_t)(b * 2 + 0) * 64 + mtile) * 64 + t;
    const size_t b1 = ((size_t)(b * 2 + 1) * 64 + mtile) * 64 + t;
    const float m0v = pM[b0], m1v = pM[b1];
    const float M = fmaxf(m0v, m1v);
    const float w0 = __expf(m0v - M), w1 = __expf(m1v - M);
    const float inv = gamma[0] / (pL[b0] * w0 + pL[b1] * w1);
    s0[t] = w0 * inv;
    s1[t] = w1 * inv;
  }
  __syncthreads();

  const int m = t & 63;
  const int c0 = ch * 128 + (t >> 6);
  const float sm0 = s0[m], sm1 = s1[m];
  const size_t ob0 = ((size_t)(b * 2 + 0) * 64 + mtile) * NC;
  const size_t ob1 = ((size_t)(b * 2 + 1) * 64 + mtile) * NC;
#pragma unroll 4
  for (int k = 0; k < 32; ++k) {
    const int c = c0 + k * 4;
    const float o0 = pO[(ob0 + c) * 64 + m];
    const float o1 = pO[(ob1 + c) * 64 + m];
    const size_t xi = ((size_t)b * NC + c) * NN + mtile * 64 + m;
    out[xi] = o0 * sm0 + o1 * sm1 + x[xi];
  }
}

extern "C" void kernel_launch(void* const* d_in, const int* in_sizes, int n_in,
                              void* d_out, int out_size, void* d_ws, size_t ws_size,
                              hipStream_t stream) {
  const float* x     = (const float*)d_in[0];
  const float* Wq    = (const float*)d_in[1];
  const float* bq    = (const float*)d_in[2];
  const float* Wk    = (const float*)d_in[3];
  const float* bk    = (const float*)d_in[4];
  const float* Wv    = (const float*)d_in[5];
  const float* bv    = (const float*)d_in[6];
  const float* gamma = (const float*)d_in[7];
  float* out = (float*)d_out;

  char* wsp = (char*)d_ws;
  __hip_bfloat16* W16 = (__hip_bfloat16*)wsp;            wsp += (size_t)320 * NC * 2;
  __hip_bfloat16* q   = (__hip_bfloat16*)wsp;            wsp += (size_t)NB * NN * DQK * 2;
  __hip_bfloat16* kT  = (__hip_bfloat16*)wsp;            wsp += (size_t)NB * NN * DQK * 2;
  __hip_bfloat16* v   = (__hip_bfloat16*)wsp;            wsp += (size_t)NB * NC * NN * 2;
  float* pO = (float*)wsp;                               wsp += (size_t)NB * 2 * 64 * NC * 64 * 4;
  float* pM = (float*)wsp;                               wsp += (size_t)NB * 2 * 64 * 64 * 4;
  float* pL = (float*)wsp;                               wsp += (size_t)NB * 2 * 64 * 64 * 4;
  const size_t need = (size_t)(wsp - (char*)d_ws);       // ~44.5 MB
  const bool split = ws_size >= need;

  wcvt_kernel<<<dim3(80), dim3(256), 0, stream>>>(Wq, Wk, Wv, W16);
  proj_kernel<<<dim3(NN / 64, NB), dim3(256), 0, stream>>>(x, W16, bq, bk, bv, q, kT, v);
  if (split) {
    flash_kernel<1><<<dim3(NB * 64 * 2), dim3(256), 0, stream>>>(
        q, kT, v, x, gamma, out, pO, pM, pL);
    combine_kernel<<<dim3(64, 2, NB), dim3(256), 0, stream>>>(pO, pM, pL, x, gamma, out);
  } else {
    flash_kernel<0><<<dim3(NB * NN / MT), dim3(256), 0, stream>>>(
        q, kT, v, x, gamma, out, pO, pM, pL);
  }
}

// Round 6
// 170.180 us; speedup vs baseline: 1.3349x; 1.3349x over previous
//
#include <hip/hip_runtime.h>
#include <hip/hip_bf16.h>
#include <cstddef>

#define NB  4
#define NC  256
#define NN  4096
#define DQK 32
#define MT  64      // query rows per flash block
#define JT  64      // key tile per iteration
#define NIT (NN / JT)
#define PSTR 72     // P row stride in bf16 (144 B rows)
#define XSTR 40     // proj LDS row stride in bf16 (80 B rows)

typedef __attribute__((ext_vector_type(8))) short short8;
typedef __attribute__((ext_vector_type(4))) float f32x4;

#define MFMA16(a, b, c) __builtin_amdgcn_mfma_f32_16x16x32_bf16((a), (b), (c), 0, 0, 0)

__device__ inline unsigned pk2bf(float a, float b) {
  __hip_bfloat162 h = __float22bfloat162_rn(make_float2(a, b));
  unsigned u;
  __builtin_memcpy(&u, &h, 4);
  return u;
}

// ---- W convert: [Wq(32);Wk(32);Wv(256)] f32 -> W16[320][256] bf16 ----
__global__ __launch_bounds__(256) void wcvt_kernel(
    const float* __restrict__ Wq, const float* __restrict__ Wk,
    const float* __restrict__ Wv, __hip_bfloat16* __restrict__ W16) {
  const int id4 = (blockIdx.x * 256 + threadIdx.x) * 4;   // 80 blocks -> 81920
  const int row = id4 >> 8, col = id4 & 255;
  const float* src = (row < 32) ? Wq + row * 256
                   : (row < 64) ? Wk + (row - 32) * 256
                                : Wv + (row - 64) * 256;
  float4 vv = *(const float4*)(src + col);
  *(uint2*)(W16 + id4) = make_uint2(pk2bf(vv.x, vv.y), pk2bf(vv.z, vv.w));
}

// ---- fused proj: D[320 o][32 n] per block; x read direct; 2-3 blocks/CU ----
__global__ __launch_bounds__(256) void proj_kernel(
    const float* __restrict__ x, const __hip_bfloat16* __restrict__ W16,
    const float* __restrict__ bq, const float* __restrict__ bk,
    const float* __restrict__ bv, __hip_bfloat16* __restrict__ q,
    __hip_bfloat16* __restrict__ kT, __hip_bfloat16* __restrict__ v) {
  __shared__ __hip_bfloat16 Xs[32 * XSTR];   // 2560 B
  const int t = threadIdx.x;
  const int b = blockIdx.y, n0 = blockIdx.x * 32;
  const int w = __builtin_amdgcn_readfirstlane(t >> 6);   // wave: o rows [w*80, w*80+80)
  const int ln = t & 15, quad = (t & 63) >> 4;
  const int sn = t & 31, scg = t >> 5;   // staging: n lane, c-group (8 groups of 4)

  f32x4 zero4 = {0.f, 0.f, 0.f, 0.f};
  f32x4 acc[5][2];
#pragma unroll
  for (int i = 0; i < 5; ++i)
#pragma unroll
    for (int j = 0; j < 2; ++j) acc[i][j] = zero4;

  const float* xsrc = x + (size_t)b * NC * NN + n0 + sn;
  float xr[4];
#pragma unroll
  for (int i = 0; i < 4; ++i) xr[i] = xsrc[(size_t)(scg * 4 + i) * NN];

  for (int k0 = 0; k0 < NC; k0 += 32) {
    const unsigned px0 = pk2bf(xr[0], xr[1]);
    const unsigned px1 = pk2bf(xr[2], xr[3]);
    __syncthreads();                       // prior step's LDS reads done
    *(uint2*)&Xs[sn * XSTR + scg * 4] = make_uint2(px0, px1);
    __syncthreads();                       // writes visible
    const int kn = k0 + 32;
    if (kn < NC) {
#pragma unroll
      for (int i = 0; i < 4; ++i) xr[i] = xsrc[(size_t)(kn + scg * 4 + i) * NN];
    }
    short8 af[5], bfr[2];
#pragma unroll
    for (int ot = 0; ot < 5; ++ot)
      af[ot] = *(const short8*)(W16 + (size_t)(w * 80 + ot * 16 + ln) * NC + k0 + quad * 8);
#pragma unroll
    for (int nt = 0; nt < 2; ++nt)
      bfr[nt] = *(const short8*)&Xs[(nt * 16 + ln) * XSTR + quad * 8];
#pragma unroll
    for (int ot = 0; ot < 5; ++ot)
#pragma unroll
      for (int nt = 0; nt < 2; ++nt)
        acc[ot][nt] = MFMA16(af[ot], bfr[nt], acc[ot][nt]);
  }

  // epilogue: rows [0,32)->q[b][n][o], [32,64)->kT[b][n][o], [64,320)->v[b][c][n]
#pragma unroll
  for (int ot = 0; ot < 5; ++ot) {
    const int gbase = w * 80 + ot * 16;    // wave-uniform
    if (gbase < 32) {
#pragma unroll
      for (int nt = 0; nt < 2; ++nt)
#pragma unroll
        for (int r = 0; r < 4; ++r) {
          const int row = gbase + quad * 4 + r;
          q[((size_t)b * NN + n0 + nt * 16 + ln) * DQK + row] =
              __hip_bfloat16(acc[ot][nt][r] + bq[row]);
        }
    } else if (gbase < 64) {
#pragma unroll
      for (int nt = 0; nt < 2; ++nt)
#pragma unroll
        for (int r = 0; r < 4; ++r) {
          const int row = gbase - 32 + quad * 4 + r;
          kT[((size_t)b * NN + n0 + nt * 16 + ln) * DQK + row] =
              __hip_bfloat16(acc[ot][nt][r] + bk[row]);
        }
    } else {
#pragma unroll
      for (int nt = 0; nt < 2; ++nt)
#pragma unroll
        for (int r = 0; r < 4; ++r) {
          const int c = gbase - 64 + quad * 4 + r;
          v[((size_t)b * NC + c) * NN + n0 + nt * 16 + ln] =
              __hip_bfloat16(acc[ot][nt][r] + bv[c]);
        }
    }
  }
}

// ---- wave-specialized flash: waves 0-3 produce P (QK+softmax), waves 4-7
// ---- consume (PV), one iteration behind, double-buffered P, 1 barrier/iter.
__global__ __launch_bounds__(512, 2) void flash_kernel(
    const __hip_bfloat16* __restrict__ q, const __hip_bfloat16* __restrict__ kt,
    const __hip_bfloat16* __restrict__ v, const float* __restrict__ x,
    const float* __restrict__ gamma, float* __restrict__ out) {
  __shared__ __hip_bfloat16 Ps[2][MT * PSTR];   // 18432 B
  __shared__ float arow[2][MT];
  __shared__ float lrow[MT];

  const int t  = threadIdx.x;
  const int bi = blockIdx.x;
  // XCD swizzle: XCD pair {2b,2b+1} serves batch b -> V slice ~2 MB in L2
  const int b  = (bi & 7) >> 1;
  const int m0 = (((bi & 1) * 32) + (bi >> 3)) * MT;

  const int w    = __builtin_amdgcn_readfirstlane(t >> 6);   // 0..7
  const int ln   = t & 15;
  const int quad = (t & 63) >> 4;

  const __hip_bfloat16* kb_base = kt + (size_t)b * NN * DQK;
  const __hip_bfloat16* v_base  = v + (size_t)b * NC * NN;

  if (w < 4) {
    // ---------------- producer: rows [m0+w*16, m0+w*16+16) ----------------
    const short8 qa =
        *(const short8*)(q + ((size_t)b * NN + m0 + w * 16 + ln) * DQK + quad * 8);
    float mreg[4], lreg[4];
#pragma unroll
    for (int r = 0; r < 4; ++r) { mreg[r] = -3.0e38f; lreg[r] = 0.f; }

    f32x4 zero4 = {0.f, 0.f, 0.f, 0.f};
    short8 kb[4];
#pragma unroll
    for (int jt = 0; jt < 4; ++jt)
      kb[jt] = *(const short8*)(kb_base + (size_t)(jt * 16 + ln) * DQK + quad * 8);

    for (int it = 0; it < NIT; ++it) {
      // S strip: 16 m x 64 j, in registers
      f32x4 sf[4];
#pragma unroll
      for (int jt = 0; jt < 4; ++jt) sf[jt] = MFMA16(qa, kb[jt], zero4);

      // prefetch next K (register, 1-iter distance)
      if (it + 1 < NIT) {
        const int jn = (it + 1) * JT;
#pragma unroll
        for (int jt = 0; jt < 4; ++jt)
          kb[jt] = *(const short8*)(kb_base + (size_t)(jn + jt * 16 + ln) * DQK + quad * 8);
      }

      // wave-local online softmax (rows quad*4+r, cols jt*16+ln)
      float rmax[4];
#pragma unroll
      for (int r = 0; r < 4; ++r)
        rmax[r] = fmaxf(fmaxf(sf[0][r], sf[1][r]), fmaxf(sf[2][r], sf[3][r]));
#pragma unroll
      for (int off = 1; off < 16; off <<= 1)
#pragma unroll
        for (int r = 0; r < 4; ++r)
          rmax[r] = fmaxf(rmax[r], __shfl_xor(rmax[r], off));
      float alpha[4];
#pragma unroll
      for (int r = 0; r < 4; ++r) {
        const float mn = fmaxf(mreg[r], rmax[r]);
        alpha[r] = __expf(mreg[r] - mn);
        mreg[r] = mn;
      }
      float e[4][4], rsum[4];
#pragma unroll
      for (int r = 0; r < 4; ++r) rsum[r] = 0.f;
#pragma unroll
      for (int jt = 0; jt < 4; ++jt)
#pragma unroll
        for (int r = 0; r < 4; ++r) {
          e[jt][r] = __expf(sf[jt][r] - mreg[r]);
          rsum[r] += e[jt][r];
        }
#pragma unroll
      for (int off = 1; off < 16; off <<= 1)
#pragma unroll
        for (int r = 0; r < 4; ++r) rsum[r] += __shfl_xor(rsum[r], off);
#pragma unroll
      for (int r = 0; r < 4; ++r) lreg[r] = lreg[r] * alpha[r] + rsum[r];

      // publish P tile + alpha
      const int buf = it & 1;
#pragma unroll
      for (int jt = 0; jt < 4; ++jt)
#pragma unroll
        for (int r = 0; r < 4; ++r)
          Ps[buf][(w * 16 + quad * 4 + r) * PSTR + jt * 16 + ln] = __hip_bfloat16(e[jt][r]);
      if (ln == 0) {
#pragma unroll
        for (int r = 0; r < 4; ++r) arow[buf][w * 16 + quad * 4 + r] = alpha[r];
      }
      __syncthreads();   // barrier #(it+1)
    }
    if (ln == 0) {
#pragma unroll
      for (int r = 0; r < 4; ++r) lrow[w * 16 + quad * 4 + r] = lreg[r];
    }
    __syncthreads();     // barrier #(NIT+1)
  } else {
    // ---------------- consumer: channels [c0, c0+64), one iter behind ----------------
    const int c0 = (w - 4) * 64;
    f32x4 zero4 = {0.f, 0.f, 0.f, 0.f};
    f32x4 acc[4][4];   // rows c = c0+ct*16+quad*4+r, cols m = mt*16+ln
#pragma unroll
    for (int ct = 0; ct < 4; ++ct)
#pragma unroll
      for (int mt = 0; mt < 4; ++mt) acc[ct][mt] = zero4;

    short8 va[4][2];
#pragma unroll
    for (int ct = 0; ct < 4; ++ct)
#pragma unroll
      for (int ks = 0; ks < 2; ++ks)
        va[ct][ks] = *(const short8*)(v_base +
            (size_t)(c0 + ct * 16 + ln) * NN + ks * 32 + quad * 8);
    __syncthreads();   // barrier #1 (aligns with producer it=0)

    for (int it = 1; it < NIT; ++it) {
      const int pbuf = (it - 1) & 1;
      float av[4];
#pragma unroll
      for (int mt = 0; mt < 4; ++mt) av[mt] = arow[pbuf][mt * 16 + ln];
#pragma unroll
      for (int ct = 0; ct < 4; ++ct)
#pragma unroll
        for (int mt = 0; mt < 4; ++mt) acc[ct][mt] *= av[mt];

#pragma unroll
      for (int ks = 0; ks < 2; ++ks) {
        short8 pb[4];
#pragma unroll
        for (int mt = 0; mt < 4; ++mt)
          pb[mt] = *(const short8*)&Ps[pbuf][(mt * 16 + ln) * PSTR + ks * 32 + quad * 8];
#pragma unroll
        for (int ct = 0; ct < 4; ++ct)
#pragma unroll
          for (int mt = 0; mt < 4; ++mt)
            acc[ct][mt] = MFMA16(va[ct][ks], pb[mt], acc[ct][mt]);
      }

      // load V(it) for next iteration (regs reused after MFMA consumption)
      const int j0 = it * JT;
#pragma unroll
      for (int ct = 0; ct < 4; ++ct)
#pragma unroll
        for (int ks = 0; ks < 2; ++ks)
          va[ct][ks] = *(const short8*)(v_base +
              (size_t)(c0 + ct * 16 + ln) * NN + j0 + ks * 32 + quad * 8);
      __syncthreads();   // barrier #(it+1)
    }

    // final PV for tile NIT-1 (pbuf = (NIT-1)&1)
    {
      const int pbuf = (NIT - 1) & 1;
      float av[4];
#pragma unroll
      for (int mt = 0; mt < 4; ++mt) av[mt] = arow[pbuf][mt * 16 + ln];
#pragma unroll
      for (int ct = 0; ct < 4; ++ct)
#pragma unroll
        for (int mt = 0; mt < 4; ++mt) acc[ct][mt] *= av[mt];
#pragma unroll
      for (int ks = 0; ks < 2; ++ks) {
        short8 pb[4];
#pragma unroll
        for (int mt = 0; mt < 4; ++mt)
          pb[mt] = *(const short8*)&Ps[pbuf][(mt * 16 + ln) * PSTR + ks * 32 + quad * 8];
#pragma unroll
        for (int ct = 0; ct < 4; ++ct)
#pragma unroll
          for (int mt = 0; mt < 4; ++mt)
            acc[ct][mt] = MFMA16(va[ct][ks], pb[mt], acc[ct][mt]);
      }
    }
    __syncthreads();     // barrier #(NIT+1): lrow visible

    // epilogue: out[b][c][m] = gamma*(O'/l) + x
    const float g0 = gamma[0];
    float li[4];
#pragma unroll
    for (int mt = 0; mt < 4; ++mt) li[mt] = 1.f / lrow[mt * 16 + ln];
#pragma unroll
    for (int ct = 0; ct < 4; ++ct)
#pragma unroll
      for (int r = 0; r < 4; ++r) {
        const int c = c0 + ct * 16 + quad * 4 + r;
        const float* xr = x + ((size_t)b * NC + c) * NN + m0;
        float* orow = out + ((size_t)b * NC + c) * NN + m0;
#pragma unroll
        for (int mt = 0; mt < 4; ++mt) {
          const int m = mt * 16 + ln;
          orow[m] = g0 * (acc[ct][mt][r] * li[mt]) + xr[m];
        }
      }
  }
}

extern "C" void kernel_launch(void* const* d_in, const int* in_sizes, int n_in,
                              void* d_out, int out_size, void* d_ws, size_t ws_size,
                              hipStream_t stream) {
  const float* x     = (const float*)d_in[0];
  const float* Wq    = (const float*)d_in[1];
  const float* bq    = (const float*)d_in[2];
  const float* Wk    = (const float*)d_in[3];
  const float* bk    = (const float*)d_in[4];
  const float* Wv    = (const float*)d_in[5];
  const float* bv    = (const float*)d_in[6];
  const float* gamma = (const float*)d_in[7];
  float* out = (float*)d_out;

  char* wsp = (char*)d_ws;
  __hip_bfloat16* W16 = (__hip_bfloat16*)wsp;  wsp += (size_t)320 * NC * 2;
  __hip_bfloat16* q   = (__hip_bfloat16*)wsp;  wsp += (size_t)NB * NN * DQK * 2;
  __hip_bfloat16* kT  = (__hip_bfloat16*)wsp;  wsp += (size_t)NB * NN * DQK * 2;
  __hip_bfloat16* v   = (__hip_bfloat16*)wsp;  // + 8.4 MB => ~10.6 MB total

  wcvt_kernel<<<dim3(80), dim3(256), 0, stream>>>(Wq, Wk, Wv, W16);
  proj_kernel<<<dim3(NN / 32, NB), dim3(256), 0, stream>>>(x, W16, bq, bk, bv, q, kT, v);
  flash_kernel<<<dim3(NB * NN / MT), dim3(512), 0, stream>>>(q, kT, v, x, gamma, out);
}